// Round 3
// baseline (706.906 us; speedup 1.0000x reference)
//
#include <hip/hip_runtime.h>
#include <hip/hip_fp16.h>
#include <math.h>

#define SCALE 0.4082482904638631f   // 1/sqrt(6)

#define BATCH 8
#define CIN   48
#define HW    256
#define NPIX  65536

// ---------------- workspace layout ----------------
// half region first, then float region.
#define QKV_H_OFF  0
#define QKV_H_SIZE ((size_t)BATCH*144*NPIX)        // 75,497,472 halves (151 MB)
#define VP_H_OFF   (QKV_H_OFF + QKV_H_SIZE)
#define VP_H_SIZE  ((size_t)BATCH*48*NPIX)         // 25,165,824 halves (50 MB)
#define F_BYTE_OFF ((VP_H_OFF + VP_H_SIZE) * 2)    // byte offset of float region
#define GP_SIZE    (BATCH*64*8*48)                 // 196,608 floats
#define M_SIZE     (BATCH*48*48)

// ===========================================================================
// K_a: 1x1 conv (48 -> 144), fp32 in, fp16 out.
// One pixel/thread; x held in 48 VGPRs (launch_bounds(256,4) -> 128 VGPR
// budget, so the allocator can actually keep them); oc in chunks of 16.
// Weights are wave-uniform -> s_load broadcast (lgkmcnt, independent of the
// global-load vmcnt pipe).
// ===========================================================================
__global__ __launch_bounds__(256, 4) void ka_conv1(
    const float* __restrict__ x, const float* __restrict__ w1,
    __half* __restrict__ qkv)
{
  const int g = blockIdx.x * 256 + threadIdx.x;
  const int b = g >> 16;
  const int n = g & 65535;
  const float* xb = x + ((size_t)b * CIN) * NPIX + n;
  float xv[48];
#pragma unroll
  for (int ic = 0; ic < 48; ++ic) xv[ic] = xb[(size_t)ic * NPIX];
  __half* ob = qkv + ((size_t)b * 144) * NPIX + n;
#pragma unroll 1
  for (int oc0 = 0; oc0 < 144; oc0 += 16) {
    float acc[16];
#pragma unroll
    for (int j = 0; j < 16; ++j) acc[j] = 0.0f;
#pragma unroll
    for (int ic = 0; ic < 48; ++ic) {
      const float xr = xv[ic];
#pragma unroll
      for (int j = 0; j < 16; ++j)
        acc[j] = fmaf(w1[(oc0 + j) * 48 + ic], xr, acc[j]);
    }
#pragma unroll
    for (int j = 0; j < 16; ++j)
      ob[(size_t)(oc0 + j) * NPIX] = __float2half(acc[j]);
  }
}

// ===========================================================================
// K_b: depthwise 3x3 on fp16 qkv (global reads; L1/L2 absorb halo reuse).
// Block = 256 threads, tile 64x16 px (thread = 4x1 strip).
// Per head: dw 12 q/k channels -> 48 gram partials -> LDS reduction.
// v channels dw'd and written as fp16 to vp_ws.
// LDS: 256*52*4 + 768 = 54 KB -> 2 blocks/CU; grid 512 = fully resident.
// ===========================================================================
__global__ __launch_bounds__(256) void kb_dw(
    const __half* __restrict__ qkv, const float* __restrict__ wd,
    __half* __restrict__ vp_ws, float* __restrict__ gram_part)
{
  __shared__ float red[256 * 52];
  __shared__ float pr[192];

  const int blk = blockIdx.x;
  const int b   = blk >> 6;
  const int t   = blk & 63;
  const int tx  = t & 3, ty = t >> 2;
  const int tid = threadIdx.x;
  const int x0  = tx * 64 + (tid & 15) * 4;
  const int y   = ty * 16 + (tid >> 4);
  const bool xm = (x0 > 0), xp = (x0 < 252);
  const __half* qb = qkv + ((size_t)b * 144) * NPIX;

  auto dwc = [&](int c, float* o) {
    const __half* plane = qb + (size_t)c * NPIX;
    const float* w9 = wd + c * 9;
    float rr[3][6];
#pragma unroll
    for (int dr = 0; dr < 3; ++dr) {
      const int r = y - 1 + dr;
      if ((unsigned)r < 256u) {
        const __half* rp = plane + r * 256 + x0;
        const float2 f01 = __half22float2(*(const __half2*)rp);
        const float2 f23 = __half22float2(*(const __half2*)(rp + 2));
        rr[dr][1] = f01.x; rr[dr][2] = f01.y;
        rr[dr][3] = f23.x; rr[dr][4] = f23.y;
        rr[dr][0] = xm ? __half2float(rp[-1]) : 0.0f;
        rr[dr][5] = xp ? __half2float(rp[4])  : 0.0f;
      } else {
#pragma unroll
        for (int j = 0; j < 6; ++j) rr[dr][j] = 0.0f;
      }
    }
#pragma unroll
    for (int p = 0; p < 4; ++p) {
      float s = 0.0f;
#pragma unroll
      for (int dr = 0; dr < 3; ++dr)
#pragma unroll
        for (int dx = 0; dx < 3; ++dx)
          s = fmaf(w9[dr * 3 + dx], rr[dr][p + dx], s);
      o[p] = s;
    }
  };

  for (int h = 0; h < 8; ++h) {
    float q[6][4], k[6][4];
#pragma unroll
    for (int j = 0; j < 6; ++j) dwc(6 * h + j, q[j]);
#pragma unroll
    for (int j = 0; j < 6; ++j) dwc(48 + 6 * h + j, k[j]);

    float g48[48];
#pragma unroll
    for (int d = 0; d < 6; ++d) {
      float s = 0.0f;
#pragma unroll
      for (int p = 0; p < 4; ++p) s = fmaf(q[d][p], q[d][p], s);
      g48[d] = s;
    }
#pragma unroll
    for (int e = 0; e < 6; ++e) {
      float s = 0.0f;
#pragma unroll
      for (int p = 0; p < 4; ++p) s = fmaf(k[e][p], k[e][p], s);
      g48[6 + e] = s;
    }
#pragma unroll
    for (int d = 0; d < 6; ++d)
#pragma unroll
      for (int e = 0; e < 6; ++e) {
        float s = 0.0f;
#pragma unroll
        for (int p = 0; p < 4; ++p) s = fmaf(q[d][p], k[e][p], s);
        g48[12 + 6 * d + e] = s;
      }

    float4* wrow = (float4*)(red + tid * 52);
#pragma unroll
    for (int j = 0; j < 12; ++j)
      wrow[j] = make_float4(g48[4 * j], g48[4 * j + 1], g48[4 * j + 2], g48[4 * j + 3]);
    __syncthreads();

    if (tid < 192) {
      const int vv = tid >> 2, ch = tid & 3;
      float s = 0.0f;
      const float* base = red + (ch * 64) * 52 + vv;
      for (int p = 0; p < 64; ++p) s += base[p * 52];
      pr[vv * 4 + ch] = s;
    }
    __syncthreads();
    if (tid < 48)
      gram_part[(((size_t)b * 64 + t) * 8 + h) * 48 + tid] =
          pr[tid * 4] + pr[tid * 4 + 1] + pr[tid * 4 + 2] + pr[tid * 4 + 3];
    __syncthreads();
  }

  // v channels -> fp16 vp_ws
#pragma unroll 1
  for (int c = 0; c < 48; ++c) {
    float o[4];
    dwc(96 + c, o);
    __half2* vp = (__half2*)(vp_ws + ((size_t)b * 48 + c) * NPIX + y * 256 + x0);
    vp[0] = __floats2half2_rn(o[0], o[1]);
    vp[1] = __floats2half2_rn(o[2], o[3]);
  }
}

// ===========================================================================
// K_d: per (b,head): sum 64 tile partials -> norms -> softmax -> fold W_proj
// ===========================================================================
__global__ void kd_attn(const float* __restrict__ gram_part,
                        const float* __restrict__ wp, float* __restrict__ Mmat)
{
  const int b = blockIdx.x >> 3;
  const int h = blockIdx.x & 7;
  __shared__ float S[48];
  __shared__ float attn[36];
  const int tid = threadIdx.x;   // 64 threads

  if (tid < 48) {
    float s = 0.0f;
    for (int t = 0; t < 64; ++t)
      s += gram_part[(((size_t)b * 64 + t) * 8 + h) * 48 + tid];
    S[tid] = s;
  }
  __syncthreads();
  if (tid < 36) {
    const int d = tid / 6, e = tid - 6 * d;
    const float nq = fmaxf(sqrtf(S[d]),     1e-12f);
    const float nk = fmaxf(sqrtf(S[6 + e]), 1e-12f);
    attn[tid] = S[12 + tid] / (nq * nk) * SCALE;
  }
  __syncthreads();
  if (tid < 6) {
    float m = attn[tid * 6];
    for (int e = 1; e < 6; ++e) m = fmaxf(m, attn[tid * 6 + e]);
    float ex[6]; float sum = 0.0f;
    for (int e = 0; e < 6; ++e) { ex[e] = expf(attn[tid * 6 + e] - m); sum += ex[e]; }
    const float inv = 1.0f / sum;
    for (int e = 0; e < 6; ++e) attn[tid * 6 + e] = ex[e] * inv;
  }
  __syncthreads();
  for (int i = tid; i < 288; i += 64) {
    const int c = i / 6, e = i - 6 * (i / 6);
    float s = 0.0f;
#pragma unroll
    for (int d = 0; d < 6; ++d) s += wp[c * 48 + 6 * h + d] * attn[d * 6 + e];
    Mmat[((size_t)b * 48 + c) * 48 + 6 * h + e] = s;
  }
}

// ===========================================================================
// K_e: y[b][c][n] = sum_{c'} M_b[c][c'] * v'[b][c'][n]; v' fp16, y fp32
// ===========================================================================
__global__ __launch_bounds__(256, 4) void ke_out(
    const __half* __restrict__ vp_ws, const float* __restrict__ Mmat,
    float* __restrict__ y)
{
  const int b = blockIdx.x >> 8;
  const int n = ((blockIdx.x & 255) << 8) + threadIdx.x;
  const __half* vb = vp_ws + ((size_t)b * 48) * NPIX + n;
  const float* Mb = Mmat + (size_t)b * 2304;
  float vv[48];
#pragma unroll
  for (int c = 0; c < 48; ++c) vv[c] = __half2float(vb[(size_t)c * NPIX]);
  float* yb = y + ((size_t)b * 48) * NPIX + n;
#pragma unroll 4
  for (int c = 0; c < 48; ++c) {
    float s = 0.0f;
#pragma unroll
    for (int cc = 0; cc < 48; ++cc) s = fmaf(Mb[c * 48 + cc], vv[cc], s);
    yb[(size_t)c * NPIX] = s;
  }
}

// ===========================================================================
extern "C" void kernel_launch(void* const* d_in, const int* in_sizes, int n_in,
                              void* d_out, int out_size, void* d_ws, size_t ws_size,
                              hipStream_t stream)
{
  const float* x  = (const float*)d_in[0];
  const float* w1 = (const float*)d_in[1];   // (144,48,1,1)
  const float* wd = (const float*)d_in[2];   // (144,1,3,3)
  const float* wp = (const float*)d_in[3];   // (48,48,1,1)

  __half* hws  = (__half*)d_ws;
  __half* qkv  = hws + QKV_H_OFF;
  __half* vp   = hws + VP_H_OFF;
  float*  fw   = (float*)((char*)d_ws + F_BYTE_OFF);
  float*  gp   = fw;
  float*  Mmat = fw + GP_SIZE;

  hipLaunchKernelGGL(ka_conv1, dim3(2048), dim3(256), 0, stream, x, w1, qkv);
  hipLaunchKernelGGL(kb_dw,    dim3(512),  dim3(256), 0, stream, qkv, wd, vp, gp);
  hipLaunchKernelGGL(kd_attn,  dim3(64),   dim3(64),  0, stream, gp, wp, Mmat);
  hipLaunchKernelGGL(ke_out,   dim3(2048), dim3(256), 0, stream, vp, Mmat, (float*)d_out);
}